// Round 8
// baseline (2382.342 us; speedup 1.0000x reference)
//
#include <hip/hip_runtime.h>
#include <math.h>

#define LVLS 16
#define TMASK ((1u << 19) - 1u)
#define NT 256
#define TSLICE (1u << 20)   // floats per level slice (T*F)
#define KPL (1u << 19)      // table entries per level

typedef _Float16 h4 __attribute__((ext_vector_type(4)));
typedef short bf8i __attribute__((ext_vector_type(8)));   // 8 bf16 in 4 VGPRs
typedef float f4 __attribute__((ext_vector_type(4)));

#define ESCALE 1024.0f
#define EINV   0.0009765625f   // 1/1024, exact

struct ResParams { float rf[LVLS]; };

__device__ __forceinline__ unsigned hash3(unsigned ux, unsigned uy, unsigned uz) {
    return ux ^ (uy * 2654435761u) ^ (uz * 805459861u);
}

__device__ __forceinline__ unsigned short bf16_rne(float f) {
    unsigned u = __builtin_bit_cast(unsigned, f);
    unsigned r = (u + 0x7FFFu + ((u >> 16) & 1u)) >> 16;
    return (unsigned short)r;
}
__device__ __forceinline__ float bf16_to_f(unsigned short h) {
    unsigned u = ((unsigned)h) << 16;
    return __builtin_bit_cast(float, u);
}
__device__ __forceinline__ void split8(const float* v, bf8i& h, bf8i& l) {
    #pragma unroll
    for (int j = 0; j < 8; ++j) {
        unsigned short hb = bf16_rne(v[j]);
        h[j] = (short)hb;
        l[j] = (short)bf16_rne(v[j] - bf16_to_f(hb));
    }
}

// ---- build fused f16 table E[l][k] = 1024*{tab_s[l][k], time-blended tab_d[l][k]} ----
__global__ __launch_bounds__(NT, 8)
void build_E(const float* __restrict__ tabs, const float* __restrict__ tabd,
             const float* __restrict__ t_ptr, h4* __restrict__ E, ResParams rp)
{
    const unsigned idx = blockIdx.x * NT + threadIdx.x;
    const unsigned l = idx >> 19;
    const unsigned k = idx & TMASK;
    const float r = rp.rf[l];
    const float tt = t_ptr[0];
    const float ft = tt * r;
    const float gt = floorf(ft);
    const float wt = ft - gt;
    const unsigned ut = (unsigned)(int)gt;
    const unsigned c0 = (ut * 3674653429u) & TMASK;
    const unsigned c1 = ((ut + 1u) * 3674653429u) & TMASK;
    const float* ts = tabs + (size_t)l * TSLICE;
    const float* td = tabd + (size_t)l * TSLICE;
    const float2 s  = *(const float2*)(ts + (size_t)k * 2u);
    const float2 d0 = *(const float2*)(td + (size_t)(k ^ c0) * 2u);
    const float2 d1 = *(const float2*)(td + (size_t)(k ^ c1) * 2u);
    const float om = 1.f - wt;
    h4 v;
    v.x = (_Float16)(s.x * ESCALE);
    v.y = (_Float16)(s.y * ESCALE);
    v.z = (_Float16)((om * d0.x + wt * d1.x) * ESCALE);
    v.w = (_Float16)((om * d0.y + wt * d1.y) * ESCALE);
    E[idx] = v;
}

// ---- pre-split weights into per-lane MFMA B-fragment order (bf16 hi/lo) --------------
__global__ __launch_bounds__(NT)
void build_W(const float* __restrict__ w10, const float* __restrict__ w11,
             const float* __restrict__ w12, const float* __restrict__ w20,
             const float* __restrict__ w21, const float* __restrict__ w22,
             unsigned short* __restrict__ Wf)
{
    const int tid = blockIdx.x * NT + threadIdx.x;
    if (tid >= 6 * 4 * 2 * 64) return;
    const int lane = tid & 63;
    const int ks = (tid >> 6) & 1;
    const int nt = (tid >> 7) & 3;
    const int L  = tid >> 9;
    const int g = lane >> 4, c = lane & 15;
    unsigned short* dst = Wf + (size_t)tid * 16;
    #pragma unroll
    for (int j = 0; j < 8; ++j) {
        const int k = ks * 32 + g * 8 + j;
        float v;
        if      (L == 0) v = w10[k * 64 + nt * 16 + c];
        else if (L == 1) v = w11[k * 64 + nt * 16 + c];
        else if (L == 2) v = w12[k * 64 + nt * 16 + c];
        else if (L == 3) v = w20[k * 64 + nt * 16 + c];
        else if (L == 4) v = w21[k * 64 + nt * 16 + c];
        else             v = (nt == 0 && c == 0) ? w22[k] : 0.f;
        unsigned short hb = bf16_rne(v);
        unsigned short lb = bf16_rne(v - bf16_to_f(hb));
        dst[j]     = hb;
        dst[8 + j] = lb;
    }
}

// ---- fully fused encoder + MFMA MLP: gathers land directly in fragment layout --------
#define MLPT 128
__global__ __launch_bounds__(MLPT, 2)
void fused_all(const float* __restrict__ x, const h4* __restrict__ E,
               const uint4* __restrict__ Wf, const float* __restrict__ alpha_ptr,
               float* __restrict__ out, int npts, ResParams rp)
{
    __shared__ float XBs[2][64 * 68];   // per-wave transpose buffer (XOR-swizzled)
    const int lane = threadIdx.x & 63;
    const int wv   = threadIdx.x >> 6;
    const int base = blockIdx.x * MLPT + wv * 64;
    if (base >= npts) return;
    float* xb = XBs[wv];
    const int g = lane >> 4, c = lane & 15;
    const float alpha = alpha_ptr[0];
    const float oma = 1.f - alpha;

    // swizzled LDS index: keeps 8-float runs contiguous (b128-able), <=2-way banks
    auto xidx = [](int row, int col6) { return row * 68 + (col6 ^ ((row & 3) << 3)); };

    // per-lane level params for levels l = g*4 + jj (selected by g, no runtime array idx)
    float rj[4];
    #pragma unroll
    for (int jj = 0; jj < 4; ++jj) {
        const float rlo = (g & 1) ? rp.rf[4 + jj]  : rp.rf[jj];
        const float rhi = (g & 1) ? rp.rf[12 + jj] : rp.rf[8 + jj];
        rj[jj] = (g & 2) ? rhi : rlo;
    }

    bf8i ah[4][2], al[4][2];
    h4 featsave[4][4];   // f16 features (x1024 domain) for the blend

    // ---- encoder: lane (g,c) gathers its own fragments: pts mt*16+c, levels g*4+jj ----
    #pragma unroll
    for (int mt = 0; mt < 4; ++mt) {
        int p = base + mt * 16 + c;
        if (p >= npts) p = npts - 1;
        const float px = x[3 * p + 0];
        const float py = x[3 * p + 1];
        const float pz = x[3 * p + 2];
        float t0[8], t1[8];
        #pragma unroll
        for (int jj = 0; jj < 4; ++jj) {
            const float r = rj[jj];
            const unsigned lbase = (unsigned)(g * 4 + jj) << 19;
            const float fx = px * r, fy = py * r, fz = pz * r;
            const float gx = floorf(fx), gy = floorf(fy), gz = floorf(fz);
            const float wx = fx - gx, wy = fy - gy, wz = fz - gz;
            const unsigned ux = (unsigned)(int)gx;
            const unsigned uy = (unsigned)(int)gy;
            const unsigned uz = (unsigned)(int)gz;
            float a0 = 0.f, a1 = 0.f, b0 = 0.f, b1 = 0.f;
            #pragma unroll
            for (int cc = 0; cc < 8; ++cc) {
                const unsigned ox = (cc >> 2) & 1, oy = (cc >> 1) & 1, oz = cc & 1;
                const unsigned kk = hash3(ux + ox, uy + oy, uz + oz) & TMASK;
                const float w = (ox ? wx : 1.f - wx)
                              * (oy ? wy : 1.f - wy)
                              * (oz ? wz : 1.f - wz);
                const h4 e = E[(size_t)(lbase + kk)];
                a0 = fmaf(w, (float)e.x, a0);
                a1 = fmaf(w, (float)e.y, a1);
                b0 = fmaf(w, (float)e.z, b0);
                b1 = fmaf(w, (float)e.w, b1);
            }
            h4 v;
            v.x = (_Float16)a0; v.y = (_Float16)a1;   // f16 round-trip: matches fb path
            v.z = (_Float16)b0; v.w = (_Float16)b1;
            featsave[mt][jj] = v;
            t0[2 * jj] = (float)v.x; t0[2 * jj + 1] = (float)v.y;
            t1[2 * jj] = (float)v.z; t1[2 * jj + 1] = (float)v.w;
        }
        split8(t0, ah[mt][0], al[mt][0]);
        split8(t1, ah[mt][1], al[mt][1]);
    }

    // ---- MLP ----
    auto run_layer = [&](int Lidx, bool relu) {
        #pragma unroll
        for (int nt = 0; nt < 4; ++nt) {
            const uint4* wp0 = Wf + ((size_t)(((Lidx * 4 + nt) * 2 + 0) * 64 + lane)) * 2;
            const uint4* wp1 = Wf + ((size_t)(((Lidx * 4 + nt) * 2 + 1) * 64 + lane)) * 2;
            const bf8i wh0 = __builtin_bit_cast(bf8i, wp0[0]);
            const bf8i wl0 = __builtin_bit_cast(bf8i, wp0[1]);
            const bf8i wh1 = __builtin_bit_cast(bf8i, wp1[0]);
            const bf8i wl1 = __builtin_bit_cast(bf8i, wp1[1]);
            f4 acc[4];
            #pragma unroll
            for (int mt = 0; mt < 4; ++mt) acc[mt] = (f4){0.f, 0.f, 0.f, 0.f};
            #pragma unroll
            for (int mt = 0; mt < 4; ++mt)
                acc[mt] = __builtin_amdgcn_mfma_f32_16x16x32_bf16(ah[mt][0], wh0, acc[mt], 0, 0, 0);
            #pragma unroll
            for (int mt = 0; mt < 4; ++mt)
                acc[mt] = __builtin_amdgcn_mfma_f32_16x16x32_bf16(ah[mt][1], wh1, acc[mt], 0, 0, 0);
            #pragma unroll
            for (int mt = 0; mt < 4; ++mt)
                acc[mt] = __builtin_amdgcn_mfma_f32_16x16x32_bf16(ah[mt][0], wl0, acc[mt], 0, 0, 0);
            #pragma unroll
            for (int mt = 0; mt < 4; ++mt)
                acc[mt] = __builtin_amdgcn_mfma_f32_16x16x32_bf16(ah[mt][1], wl1, acc[mt], 0, 0, 0);
            #pragma unroll
            for (int mt = 0; mt < 4; ++mt)
                acc[mt] = __builtin_amdgcn_mfma_f32_16x16x32_bf16(al[mt][0], wh0, acc[mt], 0, 0, 0);
            #pragma unroll
            for (int mt = 0; mt < 4; ++mt)
                acc[mt] = __builtin_amdgcn_mfma_f32_16x16x32_bf16(al[mt][1], wh1, acc[mt], 0, 0, 0);
            #pragma unroll
            for (int mt = 0; mt < 4; ++mt)
              #pragma unroll
              for (int r = 0; r < 4; ++r) {
                float v = acc[mt][r];
                if (relu) v = fmaxf(v, 0.f);
                xb[xidx(mt * 16 + g * 4 + r, nt * 16 + c)] = v;
              }
        }
    };

    auto load_frags = [&](bool blend) {
        asm volatile("s_waitcnt lgkmcnt(0)" ::: "memory");   // D-writes visible to all lanes
        #pragma unroll
        for (int mt = 0; mt < 4; ++mt) {
            float t0[8], t1[8];
            #pragma unroll
            for (int j = 0; j < 8; ++j) t0[j] = xb[xidx(mt * 16 + c, g * 8 + j)];
            #pragma unroll
            for (int j = 0; j < 8; ++j) t1[j] = xb[xidx(mt * 16 + c, 32 + g * 8 + j)];
            if (blend) {
                #pragma unroll
                for (int jj = 0; jj < 4; ++jj) {
                    const h4 e = featsave[mt][jj];
                    t0[2 * jj]     = fmaf(t0[2 * jj],     alpha, oma * (float)e.x);
                    t0[2 * jj + 1] = fmaf(t0[2 * jj + 1], alpha, oma * (float)e.y);
                    t1[2 * jj]     = fmaf(t1[2 * jj],     alpha, oma * (float)e.z);
                    t1[2 * jj + 1] = fmaf(t1[2 * jj + 1], alpha, oma * (float)e.w);
                }
            }
            split8(t0, ah[mt][0], al[mt][0]);
            split8(t1, ah[mt][1], al[mt][1]);
        }
        asm volatile("s_waitcnt lgkmcnt(0)" ::: "memory");   // reads done before next writes
    };

    run_layer(0, true);
    load_frags(false);
    run_layer(1, true);
    load_frags(false);
    run_layer(2, true);
    load_frags(true);    // blend folded into net_2 input fragments
    run_layer(3, true);
    load_frags(false);
    run_layer(4, true);
    load_frags(false);

    // head: N=1 column (w22 in lanes with c==0); descale by exact 2^-10 at store
    {
        const uint4* wp0 = Wf + ((size_t)(((5 * 4 + 0) * 2 + 0) * 64 + lane)) * 2;
        const uint4* wp1 = Wf + ((size_t)(((5 * 4 + 0) * 2 + 1) * 64 + lane)) * 2;
        const bf8i wh0 = __builtin_bit_cast(bf8i, wp0[0]);
        const bf8i wl0 = __builtin_bit_cast(bf8i, wp0[1]);
        const bf8i wh1 = __builtin_bit_cast(bf8i, wp1[0]);
        const bf8i wl1 = __builtin_bit_cast(bf8i, wp1[1]);
        f4 acc[4];
        #pragma unroll
        for (int mt = 0; mt < 4; ++mt) acc[mt] = (f4){0.f, 0.f, 0.f, 0.f};
        #pragma unroll
        for (int mt = 0; mt < 4; ++mt)
            acc[mt] = __builtin_amdgcn_mfma_f32_16x16x32_bf16(ah[mt][0], wh0, acc[mt], 0, 0, 0);
        #pragma unroll
        for (int mt = 0; mt < 4; ++mt)
            acc[mt] = __builtin_amdgcn_mfma_f32_16x16x32_bf16(ah[mt][1], wh1, acc[mt], 0, 0, 0);
        #pragma unroll
        for (int mt = 0; mt < 4; ++mt)
            acc[mt] = __builtin_amdgcn_mfma_f32_16x16x32_bf16(ah[mt][0], wl0, acc[mt], 0, 0, 0);
        #pragma unroll
        for (int mt = 0; mt < 4; ++mt)
            acc[mt] = __builtin_amdgcn_mfma_f32_16x16x32_bf16(ah[mt][1], wl1, acc[mt], 0, 0, 0);
        #pragma unroll
        for (int mt = 0; mt < 4; ++mt)
            acc[mt] = __builtin_amdgcn_mfma_f32_16x16x32_bf16(al[mt][0], wh0, acc[mt], 0, 0, 0);
        #pragma unroll
        for (int mt = 0; mt < 4; ++mt)
            acc[mt] = __builtin_amdgcn_mfma_f32_16x16x32_bf16(al[mt][1], wh1, acc[mt], 0, 0, 0);
        if (c == 0) {
            #pragma unroll
            for (int mt = 0; mt < 4; ++mt) {
                const int o = base + mt * 16 + g * 4;
                const float4 st = make_float4(acc[mt][0] * EINV, acc[mt][1] * EINV,
                                              acc[mt][2] * EINV, acc[mt][3] * EINV);
                if (o + 4 <= npts) {
                    *reinterpret_cast<float4*>(&out[o]) = st;
                } else {
                    const float sv[4] = {st.x, st.y, st.z, st.w};
                    for (int k = 0; k < 4; ++k)
                        if (o + k < npts) out[o + k] = sv[k];
                }
            }
        }
    }
}

// ---- fallback: fused single kernel (round-1, passed) ---------------------------------
__global__ __launch_bounds__(NT, 2)
void hashmlp_fused(const float* __restrict__ x, const float* __restrict__ t_ptr,
                   const float* __restrict__ tab_s, const float* __restrict__ tab_d,
                   const float* __restrict__ w10, const float* __restrict__ w11,
                   const float* __restrict__ w12, const float* __restrict__ w20,
                   const float* __restrict__ w21, const float* __restrict__ w22,
                   const float* __restrict__ alpha_ptr, float* __restrict__ out,
                   int n, ResParams rp)
{
    __shared__ float smem[64 * NT];
    const int tid = threadIdx.x;
    const int gid = blockIdx.x * NT + tid;
    if (gid >= n) return;
    const float px = x[3 * gid], py = x[3 * gid + 1], pz = x[3 * gid + 2];
    const float tt = t_ptr[0];
    const float alpha = alpha_ptr[0];
    float feat[64];
    #pragma unroll
    for (int l = 0; l < LVLS; ++l) {
        const float r = rp.rf[l];
        const float fx = px * r, fy = py * r, fz = pz * r;
        const float gx = floorf(fx), gy = floorf(fy), gz = floorf(fz);
        const float wx = fx - gx, wy = fy - gy, wz = fz - gz;
        const unsigned ux = (unsigned)(int)gx, uy = (unsigned)(int)gy, uz = (unsigned)(int)gz;
        const float* tb = tab_s + ((size_t)l << 20);
        float a0 = 0.f, a1 = 0.f;
        #pragma unroll
        for (int cc = 0; cc < 8; ++cc) {
            const unsigned ox = (cc >> 2) & 1, oy = (cc >> 1) & 1, oz = cc & 1;
            const unsigned idx = hash3(ux + ox, uy + oy, uz + oz) & TMASK;
            const float w = (ox ? wx : 1.f - wx) * (oy ? wy : 1.f - wy) * (oz ? wz : 1.f - wz);
            const float2 f = *reinterpret_cast<const float2*>(tb + ((size_t)idx * 2u));
            a0 = fmaf(w, f.x, a0); a1 = fmaf(w, f.y, a1);
        }
        feat[2 * l] = a0; feat[2 * l + 1] = a1;
    }
    #pragma unroll
    for (int l = 0; l < LVLS; ++l) {
        const float r = rp.rf[l];
        const float fx = px * r, fy = py * r, fz = pz * r;
        const float gx = floorf(fx), gy = floorf(fy), gz = floorf(fz);
        const float wx = fx - gx, wy = fy - gy, wz = fz - gz;
        const unsigned ux = (unsigned)(int)gx, uy = (unsigned)(int)gy, uz = (unsigned)(int)gz;
        const float ftp = tt * r;
        const float gt = floorf(ftp);
        const float wtp = ftp - gt;
        const unsigned ut = (unsigned)(int)gt;
        const unsigned ht0 = ut * 3674653429u;
        const unsigned ht1 = (ut + 1u) * 3674653429u;
        const float* tb = tab_d + ((size_t)l << 20);
        float a0 = 0.f, a1 = 0.f;
        #pragma unroll
        for (int cc = 0; cc < 8; ++cc) {
            const unsigned ox = (cc >> 2) & 1, oy = (cc >> 1) & 1, oz = cc & 1;
            const unsigned hs = hash3(ux + ox, uy + oy, uz + oz);
            const float ws = (ox ? wx : 1.f - wx) * (oy ? wy : 1.f - wy) * (oz ? wz : 1.f - wz);
            {
                const unsigned idx = (hs ^ ht0) & TMASK;
                const float w = ws * (1.f - wtp);
                const float2 f = *reinterpret_cast<const float2*>(tb + ((size_t)idx * 2u));
                a0 = fmaf(w, f.x, a0); a1 = fmaf(w, f.y, a1);
            }
            {
                const unsigned idx = (hs ^ ht1) & TMASK;
                const float w = ws * wtp;
                const float2 f = *reinterpret_cast<const float2*>(tb + ((size_t)idx * 2u));
                a0 = fmaf(w, f.x, a0); a1 = fmaf(w, f.y, a1);
            }
        }
        feat[32 + 2 * l] = a0; feat[33 + 2 * l] = a1;
    }
    #pragma unroll
    for (int i = 0; i < 64; ++i) smem[i * NT + tid] = feat[i];
    float acc[64];
    auto layer = [&](const float* __restrict__ W, bool do_relu) {
        #pragma unroll
        for (int j = 0; j < 64; ++j) acc[j] = 0.f;
        for (int i = 0; i < 64; ++i) {
            const float fi = smem[i * NT + tid];
            const float* wr = W + i * 64;
            #pragma unroll
            for (int j = 0; j < 64; ++j) acc[j] = fmaf(fi, wr[j], acc[j]);
        }
        #pragma unroll
        for (int j = 0; j < 64; ++j) {
            const float v = do_relu ? fmaxf(acc[j], 0.f) : acc[j];
            smem[j * NT + tid] = v;
        }
    };
    layer(w10, true); layer(w11, true); layer(w12, true);
    #pragma unroll
    for (int j = 0; j < 64; ++j) {
        const float o1 = smem[j * NT + tid];
        smem[j * NT + tid] = fmaf(o1, alpha, (1.f - alpha) * feat[j]);
    }
    layer(w20, true); layer(w21, true);
    float o = 0.f;
    for (int i = 0; i < 64; ++i) o = fmaf(smem[i * NT + tid], w22[i], o);
    out[gid] = o;
}

extern "C" void kernel_launch(void* const* d_in, const int* in_sizes, int n_in,
                              void* d_out, int out_size, void* d_ws, size_t ws_size,
                              hipStream_t stream) {
    (void)n_in; (void)out_size;
    const float* x     = (const float*)d_in[0];
    const float* t     = (const float*)d_in[1];
    const float* tabs  = (const float*)d_in[2];
    const float* tabd  = (const float*)d_in[3];
    const float* w10   = (const float*)d_in[4];
    const float* w11   = (const float*)d_in[5];
    const float* w12   = (const float*)d_in[6];
    const float* w20   = (const float*)d_in[7];
    const float* w21   = (const float*)d_in[8];
    const float* w22   = (const float*)d_in[9];
    const float* alpha = (const float*)d_in[10];
    float* out = (float*)d_out;
    const int n = in_sizes[0] / 3;

    ResParams rp;
    const double b = pow(2048.0 / 16.0, 1.0 / 15.0);
    for (int l = 0; l < LVLS; ++l)
        rp.rf[l] = (float)(int)floor(16.0 * pow(b, (double)l));

    const size_t E_BYTES = (size_t)LVLS * KPL * 8u;   // 64 MB (f16x4 entries)
    const size_t W_BYTES = 128u * 1024u;              // 96KB used, pad to 128KB
    if (ws_size < E_BYTES + W_BYTES) {
        dim3 grid((n + NT - 1) / NT), block(NT);
        hipLaunchKernelGGL(hashmlp_fused, grid, block, 0, stream,
                           x, t, tabs, tabd, w10, w11, w12, w20, w21, w22,
                           alpha, out, n, rp);
        return;
    }

    h4* E = (h4*)d_ws;
    unsigned short* Wf = (unsigned short*)((char*)d_ws + E_BYTES);

    {
        const unsigned total = LVLS * KPL;
        hipLaunchKernelGGL(build_E, dim3(total / NT), dim3(NT), 0, stream,
                           tabs, tabd, t, E, rp);
        hipLaunchKernelGGL(build_W, dim3(12), dim3(NT), 0, stream,
                           w10, w11, w12, w20, w21, w22, Wf);
    }

    dim3 fgrid((unsigned)((n + MLPT - 1) / MLPT));
    hipLaunchKernelGGL(fused_all, fgrid, dim3(MLPT), 0, stream,
                       x, E, (const uint4*)Wf, alpha, out, n, rp);
}

// Round 9
// 1672.606 us; speedup vs baseline: 1.4243x; 1.4243x over previous
//
#include <hip/hip_runtime.h>
#include <math.h>

#define LVLS 16
#define TMASK ((1u << 19) - 1u)
#define NT 256
#define TSLICE (1u << 20)   // floats per level slice (T*F)
#define KPL (1u << 19)      // table entries per level

typedef _Float16 h4 __attribute__((ext_vector_type(4)));
typedef short bf8i __attribute__((ext_vector_type(8)));   // 8 bf16 in 4 VGPRs
typedef float f4 __attribute__((ext_vector_type(4)));

#define ESCALE 1024.0f
#define EINV   0.0009765625f   // 1/1024, exact

struct ResParams { float rf[LVLS]; };

__device__ __forceinline__ unsigned hash3(unsigned ux, unsigned uy, unsigned uz) {
    return ux ^ (uy * 2654435761u) ^ (uz * 805459861u);
}

__device__ __forceinline__ unsigned short bf16_rne(float f) {
    unsigned u = __builtin_bit_cast(unsigned, f);
    unsigned r = (u + 0x7FFFu + ((u >> 16) & 1u)) >> 16;
    return (unsigned short)r;
}
__device__ __forceinline__ float bf16_to_f(unsigned short h) {
    unsigned u = ((unsigned)h) << 16;
    return __builtin_bit_cast(float, u);
}

// truncation-based bf16 hi/lo split, packed pairs (cheap: ~5 VALU/elem)
__device__ __forceinline__ void split8t(const float* v, bf8i& h, bf8i& l) {
    unsigned H[4], L[4];
    #pragma unroll
    for (int p = 0; p < 4; ++p) {
        const unsigned u0 = __builtin_bit_cast(unsigned, v[2 * p]);
        const unsigned u1 = __builtin_bit_cast(unsigned, v[2 * p + 1]);
        const unsigned h0 = u0 & 0xffff0000u;
        const unsigned h1 = u1 & 0xffff0000u;
        const float l0 = v[2 * p]     - __builtin_bit_cast(float, h0);
        const float l1 = v[2 * p + 1] - __builtin_bit_cast(float, h1);
        H[p] = (u0 >> 16) | h1;
        L[p] = (__builtin_bit_cast(unsigned, l0) >> 16)
             | (__builtin_bit_cast(unsigned, l1) & 0xffff0000u);
    }
    uint4 Hv = make_uint4(H[0], H[1], H[2], H[3]);
    uint4 Lv = make_uint4(L[0], L[1], L[2], L[3]);
    h = __builtin_bit_cast(bf8i, Hv);
    l = __builtin_bit_cast(bf8i, Lv);
}

// ---- build fused f16 table E[l][k] = 1024*{tab_s[l][k], time-blended tab_d[l][k]} ----
__global__ __launch_bounds__(NT, 8)
void build_E(const float* __restrict__ tabs, const float* __restrict__ tabd,
             const float* __restrict__ t_ptr, h4* __restrict__ E, ResParams rp)
{
    const unsigned idx = blockIdx.x * NT + threadIdx.x;
    const unsigned l = idx >> 19;
    const unsigned k = idx & TMASK;
    const float r = rp.rf[l];
    const float tt = t_ptr[0];
    const float ft = tt * r;
    const float gt = floorf(ft);
    const float wt = ft - gt;
    const unsigned ut = (unsigned)(int)gt;
    const unsigned c0 = (ut * 3674653429u) & TMASK;
    const unsigned c1 = ((ut + 1u) * 3674653429u) & TMASK;
    const float* ts = tabs + (size_t)l * TSLICE;
    const float* td = tabd + (size_t)l * TSLICE;
    const float2 s  = *(const float2*)(ts + (size_t)k * 2u);
    const float2 d0 = *(const float2*)(td + (size_t)(k ^ c0) * 2u);
    const float2 d1 = *(const float2*)(td + (size_t)(k ^ c1) * 2u);
    const float om = 1.f - wt;
    h4 v;
    v.x = (_Float16)(s.x * ESCALE);
    v.y = (_Float16)(s.y * ESCALE);
    v.z = (_Float16)((om * d0.x + wt * d1.x) * ESCALE);
    v.w = (_Float16)((om * d0.y + wt * d1.y) * ESCALE);
    E[idx] = v;
}

// ---- pre-split weights into per-lane MFMA B-fragment order (bf16 hi/lo, RNE) ---------
__global__ __launch_bounds__(NT)
void build_W(const float* __restrict__ w10, const float* __restrict__ w11,
             const float* __restrict__ w12, const float* __restrict__ w20,
             const float* __restrict__ w21, const float* __restrict__ w22,
             unsigned short* __restrict__ Wf)
{
    const int tid = blockIdx.x * NT + threadIdx.x;
    if (tid >= 6 * 4 * 2 * 64) return;
    const int lane = tid & 63;
    const int ks = (tid >> 6) & 1;
    const int nt = (tid >> 7) & 3;
    const int L  = tid >> 9;
    const int g = lane >> 4, c = lane & 15;
    unsigned short* dst = Wf + (size_t)tid * 16;
    #pragma unroll
    for (int j = 0; j < 8; ++j) {
        const int k = ks * 32 + g * 8 + j;
        float v;
        if      (L == 0) v = w10[k * 64 + nt * 16 + c];
        else if (L == 1) v = w11[k * 64 + nt * 16 + c];
        else if (L == 2) v = w12[k * 64 + nt * 16 + c];
        else if (L == 3) v = w20[k * 64 + nt * 16 + c];
        else if (L == 4) v = w21[k * 64 + nt * 16 + c];
        else             v = (nt == 0 && c == 0) ? w22[k] : 0.f;
        unsigned short hb = bf16_rne(v);
        unsigned short lb = bf16_rne(v - bf16_to_f(hb));
        dst[j]     = hb;
        dst[8 + j] = lb;
    }
}

// ---- all-level encoder, 1D grid, XCD-affine level mapping (level = blockIdx & 15) ----
// With round-robin block->XCD dispatch, level l runs on XCD l%8 only, so each XCD's
// 4MB L2 holds ~1 hot slice instead of all ten. Falls back to round-6 mixing if the
// mapping heuristic doesn't hold (speed-neutral).
__global__ __launch_bounds__(NT, 8)
void enc_all(const float* __restrict__ x, const h4* __restrict__ E,
             h4* __restrict__ fb, long cp, int npts, ResParams rp)
{
    const int b = blockIdx.x;
    const int l = b & 15;
    const int gid = (b >> 4) * NT + threadIdx.x;
    if (gid >= npts) return;
    const float r = rp.rf[l];
    const h4* Es = E + (size_t)l * KPL;

    const float px = x[3 * gid + 0];
    const float py = x[3 * gid + 1];
    const float pz = x[3 * gid + 2];
    const float fx = px * r, fy = py * r, fz = pz * r;
    const float gx = floorf(fx), gy = floorf(fy), gz = floorf(fz);
    const float wx = fx - gx, wy = fy - gy, wz = fz - gz;
    const unsigned ux = (unsigned)(int)gx;
    const unsigned uy = (unsigned)(int)gy;
    const unsigned uz = (unsigned)(int)gz;
    float a0 = 0.f, a1 = 0.f, b0 = 0.f, b1 = 0.f;
    #pragma unroll
    for (int cc = 0; cc < 8; ++cc) {
        const unsigned ox = (cc >> 2) & 1, oy = (cc >> 1) & 1, oz = cc & 1;
        const unsigned kk = hash3(ux + ox, uy + oy, uz + oz) & TMASK;
        const float w = (ox ? wx : 1.f - wx)
                      * (oy ? wy : 1.f - wy)
                      * (oz ? wz : 1.f - wz);
        const h4 e = Es[kk];
        a0 = fmaf(w, (float)e.x, a0);
        a1 = fmaf(w, (float)e.y, a1);
        b0 = fmaf(w, (float)e.z, b0);
        b1 = fmaf(w, (float)e.w, b1);
    }
    h4 v;
    v.x = (_Float16)a0;  // stays in x1024 domain
    v.y = (_Float16)a1;
    v.z = (_Float16)b0;
    v.w = (_Float16)b1;
    __builtin_nontemporal_store(__builtin_bit_cast(unsigned long long, v),
                                (unsigned long long*)&fb[(size_t)l * cp + gid]);
}

// ---- MFMA MLP: wave = 64 points, trunc bf16 split, x1024 domain throughout -----------
#define MLPT 128
__global__ __launch_bounds__(MLPT)
void mlp_mfma(const h4* __restrict__ fb, long cp, const uint4* __restrict__ Wf,
              const float* __restrict__ alpha_ptr, float* __restrict__ out, int npts)
{
    __shared__ float XBs[2][64 * 68];   // per-wave 17408B transpose buffer
    const int lane = threadIdx.x & 63;
    const int wv   = threadIdx.x >> 6;
    const int base = blockIdx.x * MLPT + wv * 64;
    if (base >= npts) return;
    float* xb = XBs[wv];
    const int g = lane >> 4, c = lane & 15;
    const float alpha = alpha_ptr[0];
    const float oma = 1.f - alpha;

    bf8i ah[4][2], al[4][2];

    // initial A-fragments straight from fb (levels g*4..g*4+3 serve both ks halves)
    #pragma unroll
    for (int mt = 0; mt < 4; ++mt) {
        float t0[8], t1[8];
        #pragma unroll
        for (int jj = 0; jj < 4; ++jj) {
            const h4 e = fb[(size_t)(g * 4 + jj) * cp + base + mt * 16 + c];
            t0[2 * jj] = (float)e.x; t0[2 * jj + 1] = (float)e.y;
            t1[2 * jj] = (float)e.z; t1[2 * jj + 1] = (float)e.w;
        }
        split8t(t0, ah[mt][0], al[mt][0]);
        split8t(t1, ah[mt][1], al[mt][1]);
    }

    auto run_layer = [&](int Lidx, bool relu) {
        #pragma unroll
        for (int nt = 0; nt < 4; ++nt) {
            const uint4* wp0 = Wf + ((size_t)(((Lidx * 4 + nt) * 2 + 0) * 64 + lane)) * 2;
            const uint4* wp1 = Wf + ((size_t)(((Lidx * 4 + nt) * 2 + 1) * 64 + lane)) * 2;
            const bf8i wh0 = __builtin_bit_cast(bf8i, wp0[0]);
            const bf8i wl0 = __builtin_bit_cast(bf8i, wp0[1]);
            const bf8i wh1 = __builtin_bit_cast(bf8i, wp1[0]);
            const bf8i wl1 = __builtin_bit_cast(bf8i, wp1[1]);
            f4 acc[4];
            #pragma unroll
            for (int mt = 0; mt < 4; ++mt) acc[mt] = (f4){0.f, 0.f, 0.f, 0.f};
            #pragma unroll
            for (int mt = 0; mt < 4; ++mt)
                acc[mt] = __builtin_amdgcn_mfma_f32_16x16x32_bf16(ah[mt][0], wh0, acc[mt], 0, 0, 0);
            #pragma unroll
            for (int mt = 0; mt < 4; ++mt)
                acc[mt] = __builtin_amdgcn_mfma_f32_16x16x32_bf16(ah[mt][1], wh1, acc[mt], 0, 0, 0);
            #pragma unroll
            for (int mt = 0; mt < 4; ++mt)
                acc[mt] = __builtin_amdgcn_mfma_f32_16x16x32_bf16(ah[mt][0], wl0, acc[mt], 0, 0, 0);
            #pragma unroll
            for (int mt = 0; mt < 4; ++mt)
                acc[mt] = __builtin_amdgcn_mfma_f32_16x16x32_bf16(ah[mt][1], wl1, acc[mt], 0, 0, 0);
            #pragma unroll
            for (int mt = 0; mt < 4; ++mt)
                acc[mt] = __builtin_amdgcn_mfma_f32_16x16x32_bf16(al[mt][0], wh0, acc[mt], 0, 0, 0);
            #pragma unroll
            for (int mt = 0; mt < 4; ++mt)
                acc[mt] = __builtin_amdgcn_mfma_f32_16x16x32_bf16(al[mt][1], wh1, acc[mt], 0, 0, 0);
            #pragma unroll
            for (int mt = 0; mt < 4; ++mt)
              #pragma unroll
              for (int r = 0; r < 4; ++r) {
                float v = acc[mt][r];
                if (relu) v = fmaxf(v, 0.f);
                xb[(mt * 16 + g * 4 + r) * 68 + nt * 16 + c] = v;
              }
        }
    };

    auto load_frags = [&](bool blend) {
        asm volatile("s_waitcnt lgkmcnt(0)" ::: "memory");   // D-writes visible to all lanes
        #pragma unroll
        for (int mt = 0; mt < 4; ++mt) {
            float t0[8], t1[8];
            #pragma unroll
            for (int j = 0; j < 8; ++j) t0[j] = xb[(mt * 16 + c) * 68 + g * 8 + j];
            #pragma unroll
            for (int j = 0; j < 8; ++j) t1[j] = xb[(mt * 16 + c) * 68 + 32 + g * 8 + j];
            if (blend) {
                #pragma unroll
                for (int jj = 0; jj < 4; ++jj) {
                    const h4 e = fb[(size_t)(g * 4 + jj) * cp + base + mt * 16 + c];
                    t0[2 * jj]     = fmaf(t0[2 * jj],     alpha, oma * (float)e.x);
                    t0[2 * jj + 1] = fmaf(t0[2 * jj + 1], alpha, oma * (float)e.y);
                    t1[2 * jj]     = fmaf(t1[2 * jj],     alpha, oma * (float)e.z);
                    t1[2 * jj + 1] = fmaf(t1[2 * jj + 1], alpha, oma * (float)e.w);
                }
            }
            split8t(t0, ah[mt][0], al[mt][0]);
            split8t(t1, ah[mt][1], al[mt][1]);
        }
        asm volatile("s_waitcnt lgkmcnt(0)" ::: "memory");   // reads done before next writes
    };

    run_layer(0, true);
    load_frags(false);
    run_layer(1, true);
    load_frags(false);
    run_layer(2, true);
    load_frags(true);    // blend folded into net_2 input fragments
    run_layer(3, true);
    load_frags(false);
    run_layer(4, true);
    load_frags(false);

    // head: N=1 column (w22 in lanes with c==0); descale by exact 2^-10 at store
    {
        const uint4* wp0 = Wf + ((size_t)(((5 * 4 + 0) * 2 + 0) * 64 + lane)) * 2;
        const uint4* wp1 = Wf + ((size_t)(((5 * 4 + 0) * 2 + 1) * 64 + lane)) * 2;
        const bf8i wh0 = __builtin_bit_cast(bf8i, wp0[0]);
        const bf8i wl0 = __builtin_bit_cast(bf8i, wp0[1]);
        const bf8i wh1 = __builtin_bit_cast(bf8i, wp1[0]);
        const bf8i wl1 = __builtin_bit_cast(bf8i, wp1[1]);
        f4 acc[4];
        #pragma unroll
        for (int mt = 0; mt < 4; ++mt) acc[mt] = (f4){0.f, 0.f, 0.f, 0.f};
        #pragma unroll
        for (int mt = 0; mt < 4; ++mt)
            acc[mt] = __builtin_amdgcn_mfma_f32_16x16x32_bf16(ah[mt][0], wh0, acc[mt], 0, 0, 0);
        #pragma unroll
        for (int mt = 0; mt < 4; ++mt)
            acc[mt] = __builtin_amdgcn_mfma_f32_16x16x32_bf16(ah[mt][1], wh1, acc[mt], 0, 0, 0);
        #pragma unroll
        for (int mt = 0; mt < 4; ++mt)
            acc[mt] = __builtin_amdgcn_mfma_f32_16x16x32_bf16(ah[mt][0], wl0, acc[mt], 0, 0, 0);
        #pragma unroll
        for (int mt = 0; mt < 4; ++mt)
            acc[mt] = __builtin_amdgcn_mfma_f32_16x16x32_bf16(ah[mt][1], wl1, acc[mt], 0, 0, 0);
        #pragma unroll
        for (int mt = 0; mt < 4; ++mt)
            acc[mt] = __builtin_amdgcn_mfma_f32_16x16x32_bf16(al[mt][0], wh0, acc[mt], 0, 0, 0);
        #pragma unroll
        for (int mt = 0; mt < 4; ++mt)
            acc[mt] = __builtin_amdgcn_mfma_f32_16x16x32_bf16(al[mt][1], wh1, acc[mt], 0, 0, 0);
        if (c == 0) {
            #pragma unroll
            for (int mt = 0; mt < 4; ++mt) {
                float4 st = make_float4(acc[mt][0] * EINV, acc[mt][1] * EINV,
                                        acc[mt][2] * EINV, acc[mt][3] * EINV);
                *reinterpret_cast<float4*>(&out[base + mt * 16 + g * 4]) = st;
            }
        }
    }
}

// ---- fallback: fused single kernel (round-1, passed) ---------------------------------
__global__ __launch_bounds__(NT, 2)
void hashmlp_fused(const float* __restrict__ x, const float* __restrict__ t_ptr,
                   const float* __restrict__ tab_s, const float* __restrict__ tab_d,
                   const float* __restrict__ w10, const float* __restrict__ w11,
                   const float* __restrict__ w12, const float* __restrict__ w20,
                   const float* __restrict__ w21, const float* __restrict__ w22,
                   const float* __restrict__ alpha_ptr, float* __restrict__ out,
                   int n, ResParams rp)
{
    __shared__ float smem[64 * NT];
    const int tid = threadIdx.x;
    const int gid = blockIdx.x * NT + tid;
    if (gid >= n) return;
    const float px = x[3 * gid], py = x[3 * gid + 1], pz = x[3 * gid + 2];
    const float tt = t_ptr[0];
    const float alpha = alpha_ptr[0];
    float feat[64];
    #pragma unroll
    for (int l = 0; l < LVLS; ++l) {
        const float r = rp.rf[l];
        const float fx = px * r, fy = py * r, fz = pz * r;
        const float gx = floorf(fx), gy = floorf(fy), gz = floorf(fz);
        const float wx = fx - gx, wy = fy - gy, wz = fz - gz;
        const unsigned ux = (unsigned)(int)gx, uy = (unsigned)(int)gy, uz = (unsigned)(int)gz;
        const float* tb = tab_s + ((size_t)l << 20);
        float a0 = 0.f, a1 = 0.f;
        #pragma unroll
        for (int cc = 0; cc < 8; ++cc) {
            const unsigned ox = (cc >> 2) & 1, oy = (cc >> 1) & 1, oz = cc & 1;
            const unsigned idx = hash3(ux + ox, uy + oy, uz + oz) & TMASK;
            const float w = (ox ? wx : 1.f - wx) * (oy ? wy : 1.f - wy) * (oz ? wz : 1.f - wz);
            const float2 f = *reinterpret_cast<const float2*>(tb + ((size_t)idx * 2u));
            a0 = fmaf(w, f.x, a0); a1 = fmaf(w, f.y, a1);
        }
        feat[2 * l] = a0; feat[2 * l + 1] = a1;
    }
    #pragma unroll
    for (int l = 0; l < LVLS; ++l) {
        const float r = rp.rf[l];
        const float fx = px * r, fy = py * r, fz = pz * r;
        const float gx = floorf(fx), gy = floorf(fy), gz = floorf(fz);
        const float wx = fx - gx, wy = fy - gy, wz = fz - gz;
        const unsigned ux = (unsigned)(int)gx, uy = (unsigned)(int)gy, uz = (unsigned)(int)gz;
        const float ftp = tt * r;
        const float gt = floorf(ftp);
        const float wtp = ftp - gt;
        const unsigned ut = (unsigned)(int)gt;
        const unsigned ht0 = ut * 3674653429u;
        const unsigned ht1 = (ut + 1u) * 3674653429u;
        const float* tb = tab_d + ((size_t)l << 20);
        float a0 = 0.f, a1 = 0.f;
        #pragma unroll
        for (int cc = 0; cc < 8; ++cc) {
            const unsigned ox = (cc >> 2) & 1, oy = (cc >> 1) & 1, oz = cc & 1;
            const unsigned hs = hash3(ux + ox, uy + oy, uz + oz);
            const float ws = (ox ? wx : 1.f - wx) * (oy ? wy : 1.f - wy) * (oz ? wz : 1.f - wz);
            {
                const unsigned idx = (hs ^ ht0) & TMASK;
                const float w = ws * (1.f - wtp);
                const float2 f = *reinterpret_cast<const float2*>(tb + ((size_t)idx * 2u));
                a0 = fmaf(w, f.x, a0); a1 = fmaf(w, f.y, a1);
            }
            {
                const unsigned idx = (hs ^ ht1) & TMASK;
                const float w = ws * wtp;
                const float2 f = *reinterpret_cast<const float2*>(tb + ((size_t)idx * 2u));
                a0 = fmaf(w, f.x, a0); a1 = fmaf(w, f.y, a1);
            }
        }
        feat[32 + 2 * l] = a0; feat[33 + 2 * l] = a1;
    }
    #pragma unroll
    for (int i = 0; i < 64; ++i) smem[i * NT + tid] = feat[i];
    float acc[64];
    auto layer = [&](const float* __restrict__ W, bool do_relu) {
        #pragma unroll
        for (int j = 0; j < 64; ++j) acc[j] = 0.f;
        for (int i = 0; i < 64; ++i) {
            const float fi = smem[i * NT + tid];
            const float* wr = W + i * 64;
            #pragma unroll
            for (int j = 0; j < 64; ++j) acc[j] = fmaf(fi, wr[j], acc[j]);
        }
        #pragma unroll
        for (int j = 0; j < 64; ++j) {
            const float v = do_relu ? fmaxf(acc[j], 0.f) : acc[j];
            smem[j * NT + tid] = v;
        }
    };
    layer(w10, true); layer(w11, true); layer(w12, true);
    #pragma unroll
    for (int j = 0; j < 64; ++j) {
        const float o1 = smem[j * NT + tid];
        smem[j * NT + tid] = fmaf(o1, alpha, (1.f - alpha) * feat[j]);
    }
    layer(w20, true); layer(w21, true);
    float o = 0.f;
    for (int i = 0; i < 64; ++i) o = fmaf(smem[i * NT + tid], w22[i], o);
    out[gid] = o;
}

extern "C" void kernel_launch(void* const* d_in, const int* in_sizes, int n_in,
                              void* d_out, int out_size, void* d_ws, size_t ws_size,
                              hipStream_t stream) {
    (void)n_in; (void)out_size;
    const float* x     = (const float*)d_in[0];
    const float* t     = (const float*)d_in[1];
    const float* tabs  = (const float*)d_in[2];
    const float* tabd  = (const float*)d_in[3];
    const float* w10   = (const float*)d_in[4];
    const float* w11   = (const float*)d_in[5];
    const float* w12   = (const float*)d_in[6];
    const float* w20   = (const float*)d_in[7];
    const float* w21   = (const float*)d_in[8];
    const float* w22   = (const float*)d_in[9];
    const float* alpha = (const float*)d_in[10];
    float* out = (float*)d_out;
    const int n = in_sizes[0] / 3;

    ResParams rp;
    const double b = pow(2048.0 / 16.0, 1.0 / 15.0);
    for (int l = 0; l < LVLS; ++l)
        rp.rf[l] = (float)(int)floor(16.0 * pow(b, (double)l));

    const size_t E_BYTES = (size_t)LVLS * KPL * 8u;   // 64 MB (f16x4 entries)
    const size_t W_BYTES = 128u * 1024u;              // 96KB used, pad to 128KB
    if (ws_size < E_BYTES + W_BYTES + 256u * 1024u) {
        dim3 grid((n + NT - 1) / NT), block(NT);
        hipLaunchKernelGGL(hashmlp_fused, grid, block, 0, stream,
                           x, t, tabs, tabd, w10, w11, w12, w20, w21, w22,
                           alpha, out, n, rp);
        return;
    }

    h4* E = (h4*)d_ws;
    unsigned short* Wf = (unsigned short*)((char*)d_ws + E_BYTES);
    h4* fb = (h4*)((char*)d_ws + E_BYTES + W_BYTES);
    long cp_cap = (long)((ws_size - E_BYTES - W_BYTES) / 128u) & ~255L;  // 128 B/pt
    long cp = cp_cap < (long)n ? cp_cap : (long)n;

    {
        const unsigned total = LVLS * KPL;
        hipLaunchKernelGGL(build_E, dim3(total / NT), dim3(NT), 0, stream,
                           tabs, tabd, t, E, rp);
        hipLaunchKernelGGL(build_W, dim3(12), dim3(NT), 0, stream,
                           w10, w11, w12, w20, w21, w22, Wf);
    }

    for (long start = 0; start < n; start += cp) {
        const long m = (n - start) < cp ? (n - start) : cp;
        const unsigned ptb = (unsigned)((m + NT - 1) / NT);
        hipLaunchKernelGGL(enc_all, dim3(ptb * 16), dim3(NT), 0, stream,
                           x + 3 * start, E, fb, cp, (int)m, rp);
        dim3 mgrid((unsigned)((m + MLPT - 1) / MLPT));
        hipLaunchKernelGGL(mlp_mfma, mgrid, dim3(MLPT), 0, stream,
                           fb, cp, (const uint4*)Wf, alpha, out + start, (int)m);
    }
}

// Round 10
// 1380.292 us; speedup vs baseline: 1.7260x; 1.2118x over previous
//
#include <hip/hip_runtime.h>
#include <math.h>

#define LVLS 16
#define TMASK ((1u << 19) - 1u)
#define NT 256
#define TSLICE (1u << 20)   // floats per level slice (T*F)
#define KPL (1u << 19)      // table entries per level

typedef _Float16 h4 __attribute__((ext_vector_type(4)));
typedef short bf8i __attribute__((ext_vector_type(8)));   // 8 bf16 in 4 VGPRs
typedef float f4 __attribute__((ext_vector_type(4)));

#define ESCALE 1024.0f
#define EINV   0.0009765625f   // 1/1024, exact

struct ResParams { float rf[LVLS]; };

__device__ __forceinline__ unsigned hash3(unsigned ux, unsigned uy, unsigned uz) {
    return ux ^ (uy * 2654435761u) ^ (uz * 805459861u);
}

__device__ __forceinline__ unsigned short bf16_rne(float f) {
    unsigned u = __builtin_bit_cast(unsigned, f);
    unsigned r = (u + 0x7FFFu + ((u >> 16) & 1u)) >> 16;
    return (unsigned short)r;
}
__device__ __forceinline__ float bf16_to_f(unsigned short h) {
    unsigned u = ((unsigned)h) << 16;
    return __builtin_bit_cast(float, u);
}

// truncation-based bf16 hi/lo split, packed pairs (cheap: ~5 VALU/elem)
__device__ __forceinline__ void split8t(const float* v, bf8i& h, bf8i& l) {
    unsigned H[4], L[4];
    #pragma unroll
    for (int p = 0; p < 4; ++p) {
        const unsigned u0 = __builtin_bit_cast(unsigned, v[2 * p]);
        const unsigned u1 = __builtin_bit_cast(unsigned, v[2 * p + 1]);
        const unsigned h0 = u0 & 0xffff0000u;
        const unsigned h1 = u1 & 0xffff0000u;
        const float l0 = v[2 * p]     - __builtin_bit_cast(float, h0);
        const float l1 = v[2 * p + 1] - __builtin_bit_cast(float, h1);
        H[p] = (u0 >> 16) | h1;
        L[p] = (__builtin_bit_cast(unsigned, l0) >> 16)
             | (__builtin_bit_cast(unsigned, l1) & 0xffff0000u);
    }
    uint4 Hv = make_uint4(H[0], H[1], H[2], H[3]);
    uint4 Lv = make_uint4(L[0], L[1], L[2], L[3]);
    h = __builtin_bit_cast(bf8i, Hv);
    l = __builtin_bit_cast(bf8i, Lv);
}

// ---- build fused f16 table E[l][k] = 1024*{tab_s[l][k], time-blended tab_d[l][k]} ----
__global__ __launch_bounds__(NT, 8)
void build_E(const float* __restrict__ tabs, const float* __restrict__ tabd,
             const float* __restrict__ t_ptr, h4* __restrict__ E, ResParams rp)
{
    const unsigned idx = blockIdx.x * NT + threadIdx.x;
    const unsigned l = idx >> 19;
    const unsigned k = idx & TMASK;
    const float r = rp.rf[l];
    const float tt = t_ptr[0];
    const float ft = tt * r;
    const float gt = floorf(ft);
    const float wt = ft - gt;
    const unsigned ut = (unsigned)(int)gt;
    const unsigned c0 = (ut * 3674653429u) & TMASK;
    const unsigned c1 = ((ut + 1u) * 3674653429u) & TMASK;
    const float* ts = tabs + (size_t)l * TSLICE;
    const float* td = tabd + (size_t)l * TSLICE;
    const float2 s  = *(const float2*)(ts + (size_t)k * 2u);
    const float2 d0 = *(const float2*)(td + (size_t)(k ^ c0) * 2u);
    const float2 d1 = *(const float2*)(td + (size_t)(k ^ c1) * 2u);
    const float om = 1.f - wt;
    h4 v;
    v.x = (_Float16)(s.x * ESCALE);
    v.y = (_Float16)(s.y * ESCALE);
    v.z = (_Float16)((om * d0.x + wt * d1.x) * ESCALE);
    v.w = (_Float16)((om * d0.y + wt * d1.y) * ESCALE);
    E[idx] = v;
}

// ---- pre-split weights into per-lane MFMA B-fragment order (bf16 hi/lo, RNE) ---------
__global__ __launch_bounds__(NT)
void build_W(const float* __restrict__ w10, const float* __restrict__ w11,
             const float* __restrict__ w12, const float* __restrict__ w20,
             const float* __restrict__ w21, const float* __restrict__ w22,
             unsigned short* __restrict__ Wf)
{
    const int tid = blockIdx.x * NT + threadIdx.x;
    if (tid >= 6 * 4 * 2 * 64) return;
    const int lane = tid & 63;
    const int ks = (tid >> 6) & 1;
    const int nt = (tid >> 7) & 3;
    const int L  = tid >> 9;
    const int g = lane >> 4, c = lane & 15;
    unsigned short* dst = Wf + (size_t)tid * 16;
    #pragma unroll
    for (int j = 0; j < 8; ++j) {
        const int k = ks * 32 + g * 8 + j;
        float v;
        if      (L == 0) v = w10[k * 64 + nt * 16 + c];
        else if (L == 1) v = w11[k * 64 + nt * 16 + c];
        else if (L == 2) v = w12[k * 64 + nt * 16 + c];
        else if (L == 3) v = w20[k * 64 + nt * 16 + c];
        else if (L == 4) v = w21[k * 64 + nt * 16 + c];
        else             v = (nt == 0 && c == 0) ? w22[k] : 0.f;
        unsigned short hb = bf16_rne(v);
        unsigned short lb = bf16_rne(v - bf16_to_f(hb));
        dst[j]     = hb;
        dst[8 + j] = lb;
    }
}

// ---- all-level encoder (round-6 form): 2D grid, blockIdx.y = level -------------------
// blockIdx.x-fastest dispatch makes this de-facto level-sequential -> one hot 4MB slice
// at a time chip-wide (best measured config: ~0.50 ns/pt).
__global__ __launch_bounds__(NT, 8)
void enc_all(const float* __restrict__ x, const h4* __restrict__ E,
             h4* __restrict__ fb, long cp, int npts, ResParams rp)
{
    const int l = blockIdx.y;
    const int gid = blockIdx.x * NT + threadIdx.x;
    if (gid >= npts) return;
    const float r = rp.rf[l];
    const h4* Es = E + (size_t)l * KPL;

    const float px = x[3 * gid + 0];
    const float py = x[3 * gid + 1];
    const float pz = x[3 * gid + 2];
    const float fx = px * r, fy = py * r, fz = pz * r;
    const float gx = floorf(fx), gy = floorf(fy), gz = floorf(fz);
    const float wx = fx - gx, wy = fy - gy, wz = fz - gz;
    const unsigned ux = (unsigned)(int)gx;
    const unsigned uy = (unsigned)(int)gy;
    const unsigned uz = (unsigned)(int)gz;
    float a0 = 0.f, a1 = 0.f, b0 = 0.f, b1 = 0.f;
    #pragma unroll
    for (int cc = 0; cc < 8; ++cc) {
        const unsigned ox = (cc >> 2) & 1, oy = (cc >> 1) & 1, oz = cc & 1;
        const unsigned kk = hash3(ux + ox, uy + oy, uz + oz) & TMASK;
        const float w = (ox ? wx : 1.f - wx)
                      * (oy ? wy : 1.f - wy)
                      * (oz ? wz : 1.f - wz);
        const h4 e = Es[kk];
        a0 = fmaf(w, (float)e.x, a0);
        a1 = fmaf(w, (float)e.y, a1);
        b0 = fmaf(w, (float)e.z, b0);
        b1 = fmaf(w, (float)e.w, b1);
    }
    h4 v;
    v.x = (_Float16)a0;  // stays in x1024 domain
    v.y = (_Float16)a1;
    v.z = (_Float16)b0;
    v.w = (_Float16)b1;
    __builtin_nontemporal_store(__builtin_bit_cast(unsigned long long, v),
                                (unsigned long long*)&fb[(size_t)l * cp + gid]);
}

// ---- MFMA MLP: wave = 64 points, half-tile LDS transpose (8.7KB/wave) ----------------
#define MLPT 128
__global__ __launch_bounds__(MLPT, 4)
void mlp_mfma(const h4* __restrict__ fb, long cp, const uint4* __restrict__ Wf,
              const float* __restrict__ alpha_ptr, float* __restrict__ out, int npts)
{
    __shared__ float XBs[2][32 * 68];   // per-wave 8704B half-tile transpose buffer
    const int lane = threadIdx.x & 63;
    const int wv   = threadIdx.x >> 6;
    const int base = blockIdx.x * MLPT + wv * 64;
    if (base >= npts) return;
    float* xb = XBs[wv];
    const int g = lane >> 4, c = lane & 15;
    const float alpha = alpha_ptr[0];
    const float oma = 1.f - alpha;

    bf8i ah[4][2], al[4][2];

    // initial A-fragments straight from fb (levels g*4..g*4+3 serve both ks halves)
    #pragma unroll
    for (int mt = 0; mt < 4; ++mt) {
        float t0[8], t1[8];
        #pragma unroll
        for (int jj = 0; jj < 4; ++jj) {
            const h4 e = fb[(size_t)(g * 4 + jj) * cp + base + mt * 16 + c];
            t0[2 * jj] = (float)e.x; t0[2 * jj + 1] = (float)e.y;
            t1[2 * jj] = (float)e.z; t1[2 * jj + 1] = (float)e.w;
        }
        split8t(t0, ah[mt][0], al[mt][0]);
        split8t(t1, ah[mt][1], al[mt][1]);
    }

    // one dense layer, processed as two 32-point halves through the small LDS buffer
    auto layer = [&](int Lidx, bool blend) {
        #pragma unroll
        for (int half = 0; half < 2; ++half) {
            const int m0 = 2 * half, m1 = 2 * half + 1;
            #pragma unroll
            for (int nt = 0; nt < 4; ++nt) {
                const uint4* wp0 = Wf + ((size_t)(((Lidx * 4 + nt) * 2 + 0) * 64 + lane)) * 2;
                const uint4* wp1 = Wf + ((size_t)(((Lidx * 4 + nt) * 2 + 1) * 64 + lane)) * 2;
                const bf8i wh0 = __builtin_bit_cast(bf8i, wp0[0]);
                const bf8i wl0 = __builtin_bit_cast(bf8i, wp0[1]);
                const bf8i wh1 = __builtin_bit_cast(bf8i, wp1[0]);
                const bf8i wl1 = __builtin_bit_cast(bf8i, wp1[1]);
                f4 acc0 = (f4){0.f, 0.f, 0.f, 0.f};
                f4 acc1 = (f4){0.f, 0.f, 0.f, 0.f};
                acc0 = __builtin_amdgcn_mfma_f32_16x16x32_bf16(ah[m0][0], wh0, acc0, 0, 0, 0);
                acc1 = __builtin_amdgcn_mfma_f32_16x16x32_bf16(ah[m1][0], wh0, acc1, 0, 0, 0);
                acc0 = __builtin_amdgcn_mfma_f32_16x16x32_bf16(ah[m0][1], wh1, acc0, 0, 0, 0);
                acc1 = __builtin_amdgcn_mfma_f32_16x16x32_bf16(ah[m1][1], wh1, acc1, 0, 0, 0);
                acc0 = __builtin_amdgcn_mfma_f32_16x16x32_bf16(ah[m0][0], wl0, acc0, 0, 0, 0);
                acc1 = __builtin_amdgcn_mfma_f32_16x16x32_bf16(ah[m1][0], wl0, acc1, 0, 0, 0);
                acc0 = __builtin_amdgcn_mfma_f32_16x16x32_bf16(ah[m0][1], wl1, acc0, 0, 0, 0);
                acc1 = __builtin_amdgcn_mfma_f32_16x16x32_bf16(ah[m1][1], wl1, acc1, 0, 0, 0);
                acc0 = __builtin_amdgcn_mfma_f32_16x16x32_bf16(al[m0][0], wh0, acc0, 0, 0, 0);
                acc1 = __builtin_amdgcn_mfma_f32_16x16x32_bf16(al[m1][0], wh0, acc1, 0, 0, 0);
                acc0 = __builtin_amdgcn_mfma_f32_16x16x32_bf16(al[m0][1], wh1, acc0, 0, 0, 0);
                acc1 = __builtin_amdgcn_mfma_f32_16x16x32_bf16(al[m1][1], wh1, acc1, 0, 0, 0);
                #pragma unroll
                for (int r = 0; r < 4; ++r) {
                    xb[(0 * 16 + g * 4 + r) * 68 + nt * 16 + c] = fmaxf(acc0[r], 0.f);
                    xb[(1 * 16 + g * 4 + r) * 68 + nt * 16 + c] = fmaxf(acc1[r], 0.f);
                }
            }
            asm volatile("s_waitcnt lgkmcnt(0)" ::: "memory");   // writes visible
            #pragma unroll
            for (int q = 0; q < 2; ++q) {
                const int mt = 2 * half + q;
                float t0[8], t1[8];
                #pragma unroll
                for (int j = 0; j < 8; ++j) t0[j] = xb[(q * 16 + c) * 68 + g * 8 + j];
                #pragma unroll
                for (int j = 0; j < 8; ++j) t1[j] = xb[(q * 16 + c) * 68 + 32 + g * 8 + j];
                if (blend) {
                    #pragma unroll
                    for (int jj = 0; jj < 4; ++jj) {
                        const h4 e = fb[(size_t)(g * 4 + jj) * cp + base + mt * 16 + c];
                        t0[2 * jj]     = fmaf(t0[2 * jj],     alpha, oma * (float)e.x);
                        t0[2 * jj + 1] = fmaf(t0[2 * jj + 1], alpha, oma * (float)e.y);
                        t1[2 * jj]     = fmaf(t1[2 * jj],     alpha, oma * (float)e.z);
                        t1[2 * jj + 1] = fmaf(t1[2 * jj + 1], alpha, oma * (float)e.w);
                    }
                }
                split8t(t0, ah[mt][0], al[mt][0]);
                split8t(t1, ah[mt][1], al[mt][1]);
            }
            asm volatile("s_waitcnt lgkmcnt(0)" ::: "memory");   // reads done before reuse
        }
    };

    layer(0, false);
    layer(1, false);
    layer(2, true);    // blend folded into net_2 input fragments
    layer(3, false);
    layer(4, false);

    // head: N=1 column (w22 in lanes with c==0); descale by exact 2^-10 at store
    {
        const uint4* wp0 = Wf + ((size_t)(((5 * 4 + 0) * 2 + 0) * 64 + lane)) * 2;
        const uint4* wp1 = Wf + ((size_t)(((5 * 4 + 0) * 2 + 1) * 64 + lane)) * 2;
        const bf8i wh0 = __builtin_bit_cast(bf8i, wp0[0]);
        const bf8i wl0 = __builtin_bit_cast(bf8i, wp0[1]);
        const bf8i wh1 = __builtin_bit_cast(bf8i, wp1[0]);
        const bf8i wl1 = __builtin_bit_cast(bf8i, wp1[1]);
        f4 acc[4];
        #pragma unroll
        for (int mt = 0; mt < 4; ++mt) acc[mt] = (f4){0.f, 0.f, 0.f, 0.f};
        #pragma unroll
        for (int mt = 0; mt < 4; ++mt)
            acc[mt] = __builtin_amdgcn_mfma_f32_16x16x32_bf16(ah[mt][0], wh0, acc[mt], 0, 0, 0);
        #pragma unroll
        for (int mt = 0; mt < 4; ++mt)
            acc[mt] = __builtin_amdgcn_mfma_f32_16x16x32_bf16(ah[mt][1], wh1, acc[mt], 0, 0, 0);
        #pragma unroll
        for (int mt = 0; mt < 4; ++mt)
            acc[mt] = __builtin_amdgcn_mfma_f32_16x16x32_bf16(ah[mt][0], wl0, acc[mt], 0, 0, 0);
        #pragma unroll
        for (int mt = 0; mt < 4; ++mt)
            acc[mt] = __builtin_amdgcn_mfma_f32_16x16x32_bf16(ah[mt][1], wl1, acc[mt], 0, 0, 0);
        #pragma unroll
        for (int mt = 0; mt < 4; ++mt)
            acc[mt] = __builtin_amdgcn_mfma_f32_16x16x32_bf16(al[mt][0], wh0, acc[mt], 0, 0, 0);
        #pragma unroll
        for (int mt = 0; mt < 4; ++mt)
            acc[mt] = __builtin_amdgcn_mfma_f32_16x16x32_bf16(al[mt][1], wh1, acc[mt], 0, 0, 0);
        if (c == 0) {
            #pragma unroll
            for (int mt = 0; mt < 4; ++mt) {
                float4 st = make_float4(acc[mt][0] * EINV, acc[mt][1] * EINV,
                                        acc[mt][2] * EINV, acc[mt][3] * EINV);
                *reinterpret_cast<float4*>(&out[base + mt * 16 + g * 4]) = st;
            }
        }
    }
}

// ---- fallback: fused single kernel (round-1, passed) ---------------------------------
__global__ __launch_bounds__(NT, 2)
void hashmlp_fused(const float* __restrict__ x, const float* __restrict__ t_ptr,
                   const float* __restrict__ tab_s, const float* __restrict__ tab_d,
                   const float* __restrict__ w10, const float* __restrict__ w11,
                   const float* __restrict__ w12, const float* __restrict__ w20,
                   const float* __restrict__ w21, const float* __restrict__ w22,
                   const float* __restrict__ alpha_ptr, float* __restrict__ out,
                   int n, ResParams rp)
{
    __shared__ float smem[64 * NT];
    const int tid = threadIdx.x;
    const int gid = blockIdx.x * NT + tid;
    if (gid >= n) return;
    const float px = x[3 * gid], py = x[3 * gid + 1], pz = x[3 * gid + 2];
    const float tt = t_ptr[0];
    const float alpha = alpha_ptr[0];
    float feat[64];
    #pragma unroll
    for (int l = 0; l < LVLS; ++l) {
        const float r = rp.rf[l];
        const float fx = px * r, fy = py * r, fz = pz * r;
        const float gx = floorf(fx), gy = floorf(fy), gz = floorf(fz);
        const float wx = fx - gx, wy = fy - gy, wz = fz - gz;
        const unsigned ux = (unsigned)(int)gx, uy = (unsigned)(int)gy, uz = (unsigned)(int)gz;
        const float* tb = tab_s + ((size_t)l << 20);
        float a0 = 0.f, a1 = 0.f;
        #pragma unroll
        for (int cc = 0; cc < 8; ++cc) {
            const unsigned ox = (cc >> 2) & 1, oy = (cc >> 1) & 1, oz = cc & 1;
            const unsigned idx = hash3(ux + ox, uy + oy, uz + oz) & TMASK;
            const float w = (ox ? wx : 1.f - wx) * (oy ? wy : 1.f - wy) * (oz ? wz : 1.f - wz);
            const float2 f = *reinterpret_cast<const float2*>(tb + ((size_t)idx * 2u));
            a0 = fmaf(w, f.x, a0); a1 = fmaf(w, f.y, a1);
        }
        feat[2 * l] = a0; feat[2 * l + 1] = a1;
    }
    #pragma unroll
    for (int l = 0; l < LVLS; ++l) {
        const float r = rp.rf[l];
        const float fx = px * r, fy = py * r, fz = pz * r;
        const float gx = floorf(fx), gy = floorf(fy), gz = floorf(fz);
        const float wx = fx - gx, wy = fy - gy, wz = fz - gz;
        const unsigned ux = (unsigned)(int)gx, uy = (unsigned)(int)gy, uz = (unsigned)(int)gz;
        const float ftp = tt * r;
        const float gt = floorf(ftp);
        const float wtp = ftp - gt;
        const unsigned ut = (unsigned)(int)gt;
        const unsigned ht0 = ut * 3674653429u;
        const unsigned ht1 = (ut + 1u) * 3674653429u;
        const float* tb = tab_d + ((size_t)l << 20);
        float a0 = 0.f, a1 = 0.f;
        #pragma unroll
        for (int cc = 0; cc < 8; ++cc) {
            const unsigned ox = (cc >> 2) & 1, oy = (cc >> 1) & 1, oz = cc & 1;
            const unsigned hs = hash3(ux + ox, uy + oy, uz + oz);
            const float ws = (ox ? wx : 1.f - wx) * (oy ? wy : 1.f - wy) * (oz ? wz : 1.f - wz);
            {
                const unsigned idx = (hs ^ ht0) & TMASK;
                const float w = ws * (1.f - wtp);
                const float2 f = *reinterpret_cast<const float2*>(tb + ((size_t)idx * 2u));
                a0 = fmaf(w, f.x, a0); a1 = fmaf(w, f.y, a1);
            }
            {
                const unsigned idx = (hs ^ ht1) & TMASK;
                const float w = ws * wtp;
                const float2 f = *reinterpret_cast<const float2*>(tb + ((size_t)idx * 2u));
                a0 = fmaf(w, f.x, a0); a1 = fmaf(w, f.y, a1);
            }
        }
        feat[32 + 2 * l] = a0; feat[33 + 2 * l] = a1;
    }
    #pragma unroll
    for (int i = 0; i < 64; ++i) smem[i * NT + tid] = feat[i];
    float acc[64];
    auto layer = [&](const float* __restrict__ W, bool do_relu) {
        #pragma unroll
        for (int j = 0; j < 64; ++j) acc[j] = 0.f;
        for (int i = 0; i < 64; ++i) {
            const float fi = smem[i * NT + tid];
            const float* wr = W + i * 64;
            #pragma unroll
            for (int j = 0; j < 64; ++j) acc[j] = fmaf(fi, wr[j], acc[j]);
        }
        #pragma unroll
        for (int j = 0; j < 64; ++j) {
            const float v = do_relu ? fmaxf(acc[j], 0.f) : acc[j];
            smem[j * NT + tid] = v;
        }
    };
    layer(w10, true); layer(w11, true); layer(w12, true);
    #pragma unroll
    for (int j = 0; j < 64; ++j) {
        const float o1 = smem[j * NT + tid];
        smem[j * NT + tid] = fmaf(o1, alpha, (1.f - alpha) * feat[j]);
    }
    layer(w20, true); layer(w21, true);
    float o = 0.f;
    for (int i = 0; i < 64; ++i) o = fmaf(smem[i * NT + tid], w22[i], o);
    out[gid] = o;
}

extern "C" void kernel_launch(void* const* d_in, const int* in_sizes, int n_in,
                              void* d_out, int out_size, void* d_ws, size_t ws_size,
                              hipStream_t stream) {
    (void)n_in; (void)out_size;
    const float* x     = (const float*)d_in[0];
    const float* t     = (const float*)d_in[1];
    const float* tabs  = (const float*)d_in[2];
    const float* tabd  = (const float*)d_in[3];
    const float* w10   = (const float*)d_in[4];
    const float* w11   = (const float*)d_in[5];
    const float* w12   = (const float*)d_in[6];
    const float* w20   = (const float*)d_in[7];
    const float* w21   = (const float*)d_in[8];
    const float* w22   = (const float*)d_in[9];
    const float* alpha = (const float*)d_in[10];
    float* out = (float*)d_out;
    const int n = in_sizes[0] / 3;

    ResParams rp;
    const double b = pow(2048.0 / 16.0, 1.0 / 15.0);
    for (int l = 0; l < LVLS; ++l)
        rp.rf[l] = (float)(int)floor(16.0 * pow(b, (double)l));

    const size_t E_BYTES = (size_t)LVLS * KPL * 8u;   // 64 MB (f16x4 entries)
    const size_t W_BYTES = 128u * 1024u;              // 96KB used, pad to 128KB
    if (ws_size < E_BYTES + W_BYTES + 256u * 1024u) {
        dim3 grid((n + NT - 1) / NT), block(NT);
        hipLaunchKernelGGL(hashmlp_fused, grid, block, 0, stream,
                           x, t, tabs, tabd, w10, w11, w12, w20, w21, w22,
                           alpha, out, n, rp);
        return;
    }

    h4* E = (h4*)d_ws;
    unsigned short* Wf = (unsigned short*)((char*)d_ws + E_BYTES);
    h4* fb = (h4*)((char*)d_ws + E_BYTES + W_BYTES);
    long cp_cap = (long)((ws_size - E_BYTES - W_BYTES) / 128u) & ~255L;  // 128 B/pt
    long cp = cp_cap < (long)n ? cp_cap : (long)n;

    {
        const unsigned total = LVLS * KPL;
        hipLaunchKernelGGL(build_E, dim3(total / NT), dim3(NT), 0, stream,
                           tabs, tabd, t, E, rp);
        hipLaunchKernelGGL(build_W, dim3(12), dim3(NT), 0, stream,
                           w10, w11, w12, w20, w21, w22, Wf);
    }

    for (long start = 0; start < n; start += cp) {
        const long m = (n - start) < cp ? (n - start) : cp;
        dim3 egrid((unsigned)((m + NT - 1) / NT), LVLS);
        hipLaunchKernelGGL(enc_all, egrid, dim3(NT), 0, stream,
                           x + 3 * start, E, fb, cp, (int)m, rp);
        dim3 mgrid((unsigned)((m + MLPT - 1) / MLPT));
        hipLaunchKernelGGL(mlp_mfma, mgrid, dim3(MLPT), 0, stream,
                           fb, cp, (const uint4*)Wf, alpha, out + start, (int)m);
    }
}